// Round 11
// baseline (899.251 us; speedup 1.0000x reference)
//
#include <hip/hip_runtime.h>
#include <stdint.h>

// Problem constants (B=4, S=2048 -> T=8192 tokens)
#define T_TOK 8192
#define DIM   1024
#define NEXP  8
#define HID   2816

typedef __bf16 bf16x8 __attribute__((ext_vector_type(8)));
typedef float  f32x4  __attribute__((ext_vector_type(4)));

typedef __attribute__((address_space(3))) uint32_t lds_u32_t;
typedef __attribute__((address_space(1))) const uint32_t gbl_u32_t;

// async global->LDS, 16B per lane. LDS dest = wave-uniform base + lane*16.
// NOTE: offset arg pinned to 0 — r9/r10's nonzero imm offset is the prime
// suspect for the r10 core dump (semantics unverified; possible LDS-dest
// offset -> OOB LDS writes). Staging addressing is bit-identical to r5/r8.
__device__ __forceinline__ void gl_lds16(const void* g, void* l) {
    __builtin_amdgcn_global_load_lds((gbl_u32_t*)g, (lds_u32_t*)l, 16, 0, 0);
}

__device__ __forceinline__ uint32_t f2bf_u(float f) {
    uint32_t u = __builtin_bit_cast(uint32_t, f);
    return u + 0x7fffu + ((u >> 16) & 1u);   // RNE to bf16, top 16 bits valid
}
__device__ __forceinline__ uint32_t pack2(float a, float b) {
    return (f2bf_u(a) >> 16) | (f2bf_u(b) & 0xffff0000u);
}

// ---------------------------------------------------------------------------
// Round 11 = r8 structure + K-loop unrolled by 3 with LITERAL buffer indices
// (VALU-reduction theory: r8's VALUBusy 36% is addressing arithmetic from the
// runtime b0/b1/b2 rotation; literal indices fold every ds_read address into
// base VGPR + 16-bit imm offset). Staging uses gl_lds16 offset-0 + 64B
// pointer bump per stage — the twice-proven r5/r8 form; the r9/r10 imm-offset
// staging construct is REMOVED (kernel-attributed core dump).
// Ledger (identical counts to r5/r8): prologue STAGE(0->buf0), STAGE(1->buf1),
// vmcnt(4)+barrier; step t: STAGE(t+2 -> buf[(t+2)%3]), compute buf[t%3],
// vmcnt(4)+barrier; tail vmcnt(0)+barrier, last compute without wait.
// Quarter swizzle (r2, conflicts=0) unchanged. B stays in LDS (r7 lesson).
// ffn2 atomic-free epilogue + combine_k (r8, +10us win) unchanged.
// ---------------------------------------------------------------------------

#define WAIT4 do { asm volatile("s_waitcnt vmcnt(4)" ::: "memory"); \
    __builtin_amdgcn_s_barrier(); __builtin_amdgcn_sched_barrier(0); } while (0)
#define WAIT0 do { asm volatile("s_waitcnt vmcnt(0)" ::: "memory"); \
    __builtin_amdgcn_s_barrier(); __builtin_amdgcn_sched_barrier(0); } while (0)

// ---------------------------------------------------------------------------
// Kernel 0: fp32 -> bf16 conversion (weights + x), 8 floats/thread.
// ---------------------------------------------------------------------------
__global__ __launch_bounds__(256) void cvt_k(
    const float* __restrict__ s, unsigned short* __restrict__ d, int n8)
{
    int i = blockIdx.x * 256 + threadIdx.x;
    if (i < n8) {
        const float4* sp = (const float4*)(s + (size_t)i * 8);
        float4 a = sp[0], b = sp[1];
        uint4 o;
        o.x = pack2(a.x, a.y); o.y = pack2(a.z, a.w);
        o.z = pack2(b.x, b.y); o.w = pack2(b.z, b.w);
        ((uint4*)d)[i] = o;
    }
}

// ---------------------------------------------------------------------------
// Kernel 1: router. One wave per token, fp64 logits, top-2 + softmax,
// per-expert gather lists via atomic counters.
// ---------------------------------------------------------------------------
__global__ __launch_bounds__(256) void router_k(
    const float* __restrict__ x, const float* __restrict__ gw,
    int* __restrict__ cnt, int* __restrict__ slot_list,
    float* __restrict__ slot_w)
{
    const int wave = threadIdx.x >> 6, lane = threadIdx.x & 63;
    const int t = blockIdx.x * 4 + wave;
    const float4* xp = (const float4*)(x + (size_t)t * DIM + lane * 16);
    float4 xv[4];
#pragma unroll
    for (int i = 0; i < 4; ++i) xv[i] = xp[i];

    double lg[NEXP];
#pragma unroll
    for (int e = 0; e < NEXP; ++e) {
        const float4* gp = (const float4*)(gw + (size_t)e * DIM + lane * 16);
        double s = 0.0;
#pragma unroll
        for (int i = 0; i < 4; ++i) {
            float4 g = gp[i];
            s += (double)xv[i].x * g.x + (double)xv[i].y * g.y +
                 (double)xv[i].z * g.z + (double)xv[i].w * g.w;
        }
#pragma unroll
        for (int m = 32; m >= 1; m >>= 1) s += __shfl_xor(s, m, 64);
        lg[e] = s;
    }

    if (lane == 0) {
        int e0 = 0; double b0 = lg[0];
#pragma unroll
        for (int e = 1; e < NEXP; ++e)
            if (lg[e] > b0) { b0 = lg[e]; e0 = e; }
        int e1 = -1; double b1 = -1.0e300;
#pragma unroll
        for (int e = 0; e < NEXP; ++e)
            if (e != e0 && lg[e] > b1) { b1 = lg[e]; e1 = e; }

        float p0 = (float)(1.0 / (1.0 + exp(b1 - b0)));
        float p1 = 1.0f - p0;

        int pos0 = atomicAdd(&cnt[e0], 1);
        slot_list[e0 * T_TOK + pos0] = 2 * t;
        slot_w[2 * t] = p0;
        int pos1 = atomicAdd(&cnt[e1], 1);
        slot_list[e1 * T_TOK + pos1] = 2 * t + 1;
        slot_w[2 * t + 1] = p1;
    }
}

// ---------------------------------------------------------------------------
// Kernel 2: gathered GEMM, fused w1/w3 + SwiGLU. C-tile 128 slots x (64+64).
// grid (HID/64=44, ceilT/128, NEXP), early-exit on empty m-block.
// ---------------------------------------------------------------------------
__global__ __launch_bounds__(256) void ffn1_k(
    const unsigned short* __restrict__ xb, const unsigned short* __restrict__ w1b,
    const unsigned short* __restrict__ w3b, const int* __restrict__ cnt,
    const int* __restrict__ slot_list, unsigned short* __restrict__ h_ws)
{
    __shared__ unsigned short As[3][128 * 32];
    __shared__ unsigned short B1s[3][64 * 32];
    __shared__ unsigned short B2s[3][64 * 32];
    __shared__ int slots_s[128];

    const int e = blockIdx.z;
    const int cntE = cnt[e];
    const int m0 = blockIdx.y * 128;
    if (m0 >= cntE) return;
    const int n0 = blockIdx.x * 64;
    const int tid = threadIdx.x;
    const int wave = tid >> 6, lane = tid & 63;

    if (tid < 128) {
        int idx = m0 + tid;
        slots_s[tid] = (idx < cntE) ? slot_list[e * T_TOK + idx] : -1;
    }
    __syncthreads();

    // staging: 4 gl_lds per wave per k-step, each instr = 16 rows x 64B
    // coalesced. waves 0,1 -> A (gathered tokens); wave 2 -> w1; wave 3 -> w3.
    const int rr = lane >> 2;
    const int qsw = (lane & 3) ^ ((rr >> 1) & 3);
    const unsigned short* gsrc[4];           // advances 64B per staged k-step
    unsigned short *l0[4], *l1[4], *l2[4];   // per-buffer LDS dests (hoisted)
    if (wave < 2) {
#pragma unroll
        for (int i = 0; i < 4; ++i) {
            int row = wave * 64 + i * 16 + rr;
            int slot = slots_s[row];
            int tok = (slot >= 0) ? (slot >> 1) : 0;   // clamp tail to token 0
            gsrc[i] = xb + (size_t)tok * DIM + qsw * 8;
            l0[i] = &As[0][(wave * 64 + i * 16) * 32];
            l1[i] = &As[1][(wave * 64 + i * 16) * 32];
            l2[i] = &As[2][(wave * 64 + i * 16) * 32];
        }
    } else if (wave == 2) {
#pragma unroll
        for (int i = 0; i < 4; ++i) {
            int row = i * 16 + rr;
            gsrc[i] = w1b + ((size_t)e * HID + n0 + row) * DIM + qsw * 8;
            l0[i] = &B1s[0][(i * 16) * 32];
            l1[i] = &B1s[1][(i * 16) * 32];
            l2[i] = &B1s[2][(i * 16) * 32];
        }
    } else {
#pragma unroll
        for (int i = 0; i < 4; ++i) {
            int row = i * 16 + rr;
            gsrc[i] = w3b + ((size_t)e * HID + n0 + row) * DIM + qsw * 8;
            l0[i] = &B2s[0][(i * 16) * 32];
            l1[i] = &B2s[1][(i * 16) * 32];
            l2[i] = &B2s[2][(i * 16) * 32];
        }
    }

    const int wm = wave >> 1, wn = wave & 1;
    const int lrow = lane & 15, quad = lane >> 4;
    const int ksw = (quad ^ ((lrow >> 1) & 3)) * 8;   // swizzled k-offset

    f32x4 acc1[4][2], acc2[4][2];
    const f32x4 zf = {0.f, 0.f, 0.f, 0.f};
#pragma unroll
    for (int mi = 0; mi < 4; ++mi)
#pragma unroll
        for (int ni = 0; ni < 2; ++ni) { acc1[mi][ni] = zf; acc2[mi][ni] = zf; }

#define FFN1_STG(N) do { \
    gl_lds16(gsrc[0], l##N[0]); gl_lds16(gsrc[1], l##N[1]); \
    gl_lds16(gsrc[2], l##N[2]); gl_lds16(gsrc[3], l##N[3]); \
    gsrc[0] += 32; gsrc[1] += 32; gsrc[2] += 32; gsrc[3] += 32; } while (0)

#define FFN1_COMP(N) do { \
    bf16x8 af[4], b1f[2], b2f[2]; \
    _Pragma("unroll") \
    for (int mi = 0; mi < 4; ++mi) \
        af[mi] = *(const bf16x8*)&As[N][(wm * 64 + mi * 16 + lrow) * 32 + ksw]; \
    _Pragma("unroll") \
    for (int ni = 0; ni < 2; ++ni) { \
        b1f[ni] = *(const bf16x8*)&B1s[N][(wn * 32 + ni * 16 + lrow) * 32 + ksw]; \
        b2f[ni] = *(const bf16x8*)&B2s[N][(wn * 32 + ni * 16 + lrow) * 32 + ksw]; \
    } \
    __builtin_amdgcn_s_setprio(1); \
    _Pragma("unroll") \
    for (int mi = 0; mi < 4; ++mi) { \
        acc1[mi][0] = __builtin_amdgcn_mfma_f32_16x16x32_bf16(af[mi], b1f[0], acc1[mi][0], 0, 0, 0); \
        acc1[mi][1] = __builtin_amdgcn_mfma_f32_16x16x32_bf16(af[mi], b1f[1], acc1[mi][1], 0, 0, 0); \
        acc2[mi][0] = __builtin_amdgcn_mfma_f32_16x16x32_bf16(af[mi], b2f[0], acc2[mi][0], 0, 0, 0); \
        acc2[mi][1] = __builtin_amdgcn_mfma_f32_16x16x32_bf16(af[mi], b2f[1], acc2[mi][1], 0, 0, 0); \
    } \
    __builtin_amdgcn_s_setprio(0); } while (0)

    // prologue: stage t=0 -> buf0, t=1 -> buf1; wait t=0 (t=1 in flight).
    FFN1_STG(0);
    FFN1_STG(1);
    WAIT4;

    // main: t = 0..29 as 10 groups of 3; step t stages t+2 into buf (t+2)%3.
    for (int g = 0; g < 10; ++g) {
        FFN1_STG(2); FFN1_COMP(0); WAIT4;
        FFN1_STG(0); FFN1_COMP(1); WAIT4;
        FFN1_STG(1); FFN1_COMP(2); WAIT4;
    }
    // tail: t=30 (buf0, no stage, drain), t=31 (buf1, no wait).
    FFN1_COMP(0); WAIT0;
    FFN1_COMP(1);

#undef FFN1_STG
#undef FFN1_COMP

    // epilogue: h = silu(a1) * a3 -> bf16 h_ws[slot, n]
#pragma unroll
    for (int mi = 0; mi < 4; ++mi) {
#pragma unroll
        for (int r = 0; r < 4; ++r) {
            int mloc = wm * 64 + mi * 16 + quad * 4 + r;
            int slot = slots_s[mloc];
            if (slot >= 0) {
                unsigned short* hrow =
                    h_ws + (size_t)slot * HID + n0 + wn * 32 + lrow;
#pragma unroll
                for (int ni = 0; ni < 2; ++ni) {
                    float a1 = acc1[mi][ni][r], a3 = acc2[mi][ni][r];
                    float hv = (a1 / (1.f + __expf(-a1))) * a3;
                    hrow[ni * 16] = (unsigned short)(f2bf_u(hv) >> 16);
                }
            }
        }
    }
}

// ---------------------------------------------------------------------------
// Kernel 3: gathered GEMM y = h @ w2^T, scale by routing weight, PLAIN STORE
// into per-slot y_ws (no atomics: each (slot, col) owned by exactly one
// lane). C-tile 128 x 128. grid (DIM/128=8, ceilT/128, NEXP).
// ---------------------------------------------------------------------------
__global__ __launch_bounds__(256) void ffn2_k(
    const unsigned short* __restrict__ h_ws, const unsigned short* __restrict__ w2b,
    const int* __restrict__ cnt, const int* __restrict__ slot_list,
    const float* __restrict__ slot_w, float* __restrict__ y_ws)
{
    __shared__ unsigned short As[3][128 * 32];
    __shared__ unsigned short Bs[3][128 * 32];
    __shared__ int slots_s[128];
    __shared__ float wgt_s[128];

    const int e = blockIdx.z;
    const int cntE = cnt[e];
    const int m0 = blockIdx.y * 128;
    if (m0 >= cntE) return;
    const int n0 = blockIdx.x * 128;
    const int tid = threadIdx.x;
    const int wave = tid >> 6, lane = tid & 63;

    if (tid < 128) {
        int idx = m0 + tid;
        int s = (idx < cntE) ? slot_list[e * T_TOK + idx] : -1;
        slots_s[tid] = s;
        wgt_s[tid] = (s >= 0) ? slot_w[s] : 0.f;
    }
    __syncthreads();

    // staging: waves 0,1 -> A (gathered h rows); waves 2,3 -> w2 rows.
    const int rr = lane >> 2;
    const int qsw = (lane & 3) ^ ((rr >> 1) & 3);
    const unsigned short* gsrc[4];
    unsigned short *l0[4], *l1[4], *l2[4];
    if (wave < 2) {
#pragma unroll
        for (int i = 0; i < 4; ++i) {
            int row = wave * 64 + i * 16 + rr;
            int slot = slots_s[row];
            int s = (slot >= 0) ? slot : 0;
            gsrc[i] = h_ws + (size_t)s * HID + qsw * 8;
            l0[i] = &As[0][(wave * 64 + i * 16) * 32];
            l1[i] = &As[1][(wave * 64 + i * 16) * 32];
            l2[i] = &As[2][(wave * 64 + i * 16) * 32];
        }
    } else {
#pragma unroll
        for (int i = 0; i < 4; ++i) {
            int row = (wave - 2) * 64 + i * 16 + rr;
            gsrc[i] = w2b + ((size_t)e * DIM + n0 + row) * HID + qsw * 8;
            l0[i] = &Bs[0][((wave - 2) * 64 + i * 16) * 32];
            l1[i] = &Bs[1][((wave - 2) * 64 + i * 16) * 32];
            l2[i] = &Bs[2][((wave - 2) * 64 + i * 16) * 32];
        }
    }

    const int wm = wave >> 1, wn = wave & 1;
    const int lrow = lane & 15, quad = lane >> 4;
    const int ksw = (quad ^ ((lrow >> 1) & 3)) * 8;

    f32x4 acc[4][4];
    const f32x4 zf = {0.f, 0.f, 0.f, 0.f};
#pragma unroll
    for (int mi = 0; mi < 4; ++mi)
#pragma unroll
        for (int ni = 0; ni < 4; ++ni) acc[mi][ni] = zf;

#define FFN2_STG(N) do { \
    gl_lds16(gsrc[0], l##N[0]); gl_lds16(gsrc[1], l##N[1]); \
    gl_lds16(gsrc[2], l##N[2]); gl_lds16(gsrc[3], l##N[3]); \
    gsrc[0] += 32; gsrc[1] += 32; gsrc[2] += 32; gsrc[3] += 32; } while (0)

#define FFN2_COMP(N) do { \
    bf16x8 af[4], bf[4]; \
    _Pragma("unroll") \
    for (int mi = 0; mi < 4; ++mi) \
        af[mi] = *(const bf16x8*)&As[N][(wm * 64 + mi * 16 + lrow) * 32 + ksw]; \
    _Pragma("unroll") \
    for (int ni = 0; ni < 4; ++ni) \
        bf[ni] = *(const bf16x8*)&Bs[N][(wn * 64 + ni * 16 + lrow) * 32 + ksw]; \
    __builtin_amdgcn_s_setprio(1); \
    _Pragma("unroll") \
    for (int mi = 0; mi < 4; ++mi) { \
        acc[mi][0] = __builtin_amdgcn_mfma_f32_16x16x32_bf16(af[mi], bf[0], acc[mi][0], 0, 0, 0); \
        acc[mi][1] = __builtin_amdgcn_mfma_f32_16x16x32_bf16(af[mi], bf[1], acc[mi][1], 0, 0, 0); \
        acc[mi][2] = __builtin_amdgcn_mfma_f32_16x16x32_bf16(af[mi], bf[2], acc[mi][2], 0, 0, 0); \
        acc[mi][3] = __builtin_amdgcn_mfma_f32_16x16x32_bf16(af[mi], bf[3], acc[mi][3], 0, 0, 0); \
    } \
    __builtin_amdgcn_s_setprio(0); } while (0)

    // NST = 88. prologue: t=0 -> buf0, t=1 -> buf1; wait t=0.
    FFN2_STG(0);
    FFN2_STG(1);
    WAIT4;

    // main: t = 0..83 as 28 groups of 3 (stages t=2..85).
    for (int g = 0; g < 28; ++g) {
        FFN2_STG(2); FFN2_COMP(0); WAIT4;
        FFN2_STG(0); FFN2_COMP(1); WAIT4;
        FFN2_STG(1); FFN2_COMP(2); WAIT4;
    }
    // t=84 (buf0, stage t=86 -> buf2), t=85 (buf1, stage t=87 -> buf0)
    FFN2_STG(2); FFN2_COMP(0); WAIT4;
    FFN2_STG(0); FFN2_COMP(1); WAIT4;
    // t=86 (buf2, no stage, drain), t=87 (buf0, no wait)
    FFN2_COMP(2); WAIT0;
    FFN2_COMP(0);

#undef FFN2_STG
#undef FFN2_COMP

    // epilogue: plain stores, one owner per (slot, col).
#pragma unroll
    for (int mi = 0; mi < 4; ++mi) {
#pragma unroll
        for (int r = 0; r < 4; ++r) {
            int mloc = wm * 64 + mi * 16 + quad * 4 + r;
            int slot = slots_s[mloc];
            if (slot >= 0) {
                float w = wgt_s[mloc];
                float* yrow = y_ws + (size_t)slot * DIM + n0 + wn * 64 + lrow;
#pragma unroll
                for (int ni = 0; ni < 4; ++ni)
                    yrow[ni * 16] = acc[mi][ni][r] * w;
            }
        }
    }
}

// ---------------------------------------------------------------------------
// Kernel 4: combine. out[t] = y[2t] + y[2t+1]  (both already weight-scaled).
// ---------------------------------------------------------------------------
__global__ __launch_bounds__(256) void combine_k(
    const float* __restrict__ y, float* __restrict__ out)
{
    int i = blockIdx.x * 256 + threadIdx.x;      // i in [0, 8192*256)
    int t = i >> 8, d = i & 255;
    const float4* a = (const float4*)(y + (size_t)(2 * t) * DIM) + d;
    const float4* b = (const float4*)(y + (size_t)(2 * t + 1) * DIM) + d;
    float4 va = *a, vb = *b;
    float4 o = {va.x + vb.x, va.y + vb.y, va.z + vb.z, va.w + vb.w};
    ((float4*)(out + (size_t)t * DIM))[d] = o;
}

// ---------------------------------------------------------------------------
// Workspace layout (bytes):
//   [0, 256)                 cnt[8]                (memset 0 per launch)
//   [256, +262144)           slot_list[8][8192]
//   [+262144, +65536)        slot_w[16384]
//   [327936, +92274688)      h_ws   bf16 [16384][2816]
//   [92602624, +16777216)    x_bf   bf16 [8192][1024]
//   [109379840, +46137344)   w1_bf  bf16 [8][2816][1024]
//   [155517184, +46137344)   w3_bf
//   [201654528, +46137344)   w2_bf  bf16 [8][1024][2816]
//   y_ws f32 [16384][1024] = 67108864 B ALIASES [92602624, 159711488):
//   x_bf + w1_bf + first 4.2MB of w3_bf — all dead after ffn1 completes;
//   stream order (ffn1 -> ffn2 -> combine -> next-iter cvt) makes this safe.
// ---------------------------------------------------------------------------
extern "C" void kernel_launch(void* const* d_in, const int* in_sizes, int n_in,
                              void* d_out, int out_size, void* d_ws, size_t ws_size,
                              hipStream_t stream) {
    const float* x  = (const float*)d_in[0];
    const float* gw = (const float*)d_in[1];
    const float* w1 = (const float*)d_in[2];
    const float* w2 = (const float*)d_in[3];
    const float* w3 = (const float*)d_in[4];
    float* out = (float*)d_out;

    char* ws = (char*)d_ws;
    int*   cnt       = (int*)ws;
    int*   slot_list = (int*)(ws + 256);
    float* slot_w    = (float*)(ws + 256 + NEXP * T_TOK * 4);
    unsigned short* h_ws = (unsigned short*)(ws + 327936);
    unsigned short* x_bf = (unsigned short*)(ws + 92602624);
    unsigned short* w1_bf = (unsigned short*)(ws + 109379840);
    unsigned short* w3_bf = (unsigned short*)(ws + 155517184);
    unsigned short* w2_bf = (unsigned short*)(ws + 201654528);
    float* y_ws = (float*)(ws + 92602624);   // aliases x_bf/w1_bf (dead post-ffn1)

    hipMemsetAsync(cnt, 0, 256, stream);

    const int nx = T_TOK * DIM / 8;              // 1048576
    const int nw = NEXP * HID * DIM / 8;         // 2883584
    cvt_k<<<(nx + 255) / 256, 256, 0, stream>>>(x, x_bf, nx);
    cvt_k<<<(nw + 255) / 256, 256, 0, stream>>>(w1, w1_bf, nw);
    cvt_k<<<(nw + 255) / 256, 256, 0, stream>>>(w3, w3_bf, nw);
    cvt_k<<<(nw + 255) / 256, 256, 0, stream>>>(w2, w2_bf, nw);

    router_k<<<T_TOK / 4, 256, 0, stream>>>(x, gw, cnt, slot_list, slot_w);
    ffn1_k<<<dim3(HID / 64, T_TOK / 128, NEXP), 256, 0, stream>>>(
        x_bf, w1_bf, w3_bf, cnt, slot_list, h_ws);
    ffn2_k<<<dim3(DIM / 128, T_TOK / 128, NEXP), 256, 0, stream>>>(
        h_ws, w2_bf, cnt, slot_list, slot_w, y_ws);
    combine_k<<<T_TOK, 256, 0, stream>>>(y_ws, out);
}

// Round 12
// 875.501 us; speedup vs baseline: 1.0271x; 1.0271x over previous
//
#include <hip/hip_runtime.h>
#include <stdint.h>

// Problem constants (B=4, S=2048 -> T=8192 tokens)
#define T_TOK 8192
#define DIM   1024
#define NEXP  8
#define HID   2816

typedef __bf16 bf16x8 __attribute__((ext_vector_type(8)));
typedef float  f32x4  __attribute__((ext_vector_type(4)));

typedef __attribute__((address_space(3))) uint32_t lds_u32_t;
typedef __attribute__((address_space(1))) const uint32_t gbl_u32_t;

// async global->LDS, 16B per lane. LDS dest = wave-uniform base + lane*16.
// offset arg pinned to 0 (r10 lesson: nonzero imm offset -> core dump).
__device__ __forceinline__ void gl_lds16(const void* g, void* l) {
    __builtin_amdgcn_global_load_lds((gbl_u32_t*)g, (lds_u32_t*)l, 16, 0, 0);
}

__device__ __forceinline__ uint32_t f2bf_u(float f) {
    uint32_t u = __builtin_bit_cast(uint32_t, f);
    return u + 0x7fffu + ((u >> 16) & 1u);   // RNE to bf16, top 16 bits valid
}
__device__ __forceinline__ uint32_t pack2(float a, float b) {
    return (f2bf_u(a) >> 16) | (f2bf_u(b) & 0xffff0000u);
}

// ---------------------------------------------------------------------------
// Round 12 = r11 GEMM cores FROZEN (ffn1 plateau 255-256us across three
// schedule families with every pipe <=44% — source-level scheduling done) +
// dispatch-count consolidation 9 -> 5 to attack the ~250us gap between the
// sum of modeled kernel times (~620us) and measured total (899us):
//   - prep_k: single kernel converts w1/w3/w2 (one grid) AND zeroes cnt
//     (replaces 3 cvt launches + hipMemsetAsync).
//   - router_k: also writes x_bf (it already reads all of x) — replaces the
//     4th cvt launch and saves a 33MB re-read.
//   - ffn1/ffn2/combine: byte-identical to r11 (proven: 899us, refchecked).
// Readout: big drop => inter-dispatch overhead was real, keep consolidating;
// small drop => dispatches are cheap, next lever is 32x32 MFMA cores.
// ---------------------------------------------------------------------------

#define WAIT4 do { asm volatile("s_waitcnt vmcnt(4)" ::: "memory"); \
    __builtin_amdgcn_s_barrier(); __builtin_amdgcn_sched_barrier(0); } while (0)
#define WAIT0 do { asm volatile("s_waitcnt vmcnt(0)" ::: "memory"); \
    __builtin_amdgcn_s_barrier(); __builtin_amdgcn_sched_barrier(0); } while (0)

// ---------------------------------------------------------------------------
// Kernel 0: weight prep. fp32 -> bf16 for w1,w3,w2 in one grid; block 0 also
// zeroes the router's per-expert counters (runs before router: stream order).
// ---------------------------------------------------------------------------
__global__ __launch_bounds__(256) void prep_k(
    const float* __restrict__ w1, const float* __restrict__ w3,
    const float* __restrict__ w2, unsigned short* __restrict__ w1d,
    unsigned short* __restrict__ w3d, unsigned short* __restrict__ w2d,
    int* __restrict__ cnt)
{
    const int nw = NEXP * HID * DIM / 8;   // 2883584 groups of 8 floats
    int i = blockIdx.x * 256 + threadIdx.x;
    if (blockIdx.x == 0 && threadIdx.x < NEXP) cnt[threadIdx.x] = 0;

    const float* s;
    unsigned short* d;
    int j;
    if (i < nw)            { s = w1; d = w1d; j = i; }
    else if (i < 2 * nw)   { s = w3; d = w3d; j = i - nw; }
    else if (i < 3 * nw)   { s = w2; d = w2d; j = i - 2 * nw; }
    else return;

    const float4* sp = (const float4*)(s + (size_t)j * 8);
    float4 a = sp[0], b = sp[1];
    uint4 o;
    o.x = pack2(a.x, a.y); o.y = pack2(a.z, a.w);
    o.z = pack2(b.x, b.y); o.w = pack2(b.z, b.w);
    ((uint4*)d)[j] = o;
}

// ---------------------------------------------------------------------------
// Kernel 1: router (+ x->bf16). One wave per token, fp64 logits, top-2 +
// softmax, per-expert gather lists via atomic counters. The wave already
// holds the full token row in registers, so it also emits x_bf.
// ---------------------------------------------------------------------------
__global__ __launch_bounds__(256) void router_k(
    const float* __restrict__ x, const float* __restrict__ gw,
    unsigned short* __restrict__ x_bf,
    int* __restrict__ cnt, int* __restrict__ slot_list,
    float* __restrict__ slot_w)
{
    const int wave = threadIdx.x >> 6, lane = threadIdx.x & 63;
    const int t = blockIdx.x * 4 + wave;
    const float4* xp = (const float4*)(x + (size_t)t * DIM + lane * 16);
    float4 xv[4];
#pragma unroll
    for (int i = 0; i < 4; ++i) xv[i] = xp[i];

    // emit bf16 copy of this token row (lane covers floats [lane*16, +16))
    {
        uint4 o0, o1;
        o0.x = pack2(xv[0].x, xv[0].y); o0.y = pack2(xv[0].z, xv[0].w);
        o0.z = pack2(xv[1].x, xv[1].y); o0.w = pack2(xv[1].z, xv[1].w);
        o1.x = pack2(xv[2].x, xv[2].y); o1.y = pack2(xv[2].z, xv[2].w);
        o1.z = pack2(xv[3].x, xv[3].y); o1.w = pack2(xv[3].z, xv[3].w);
        uint4* xd = (uint4*)(x_bf + (size_t)t * DIM + lane * 16);
        xd[0] = o0; xd[1] = o1;
    }

    double lg[NEXP];
#pragma unroll
    for (int e = 0; e < NEXP; ++e) {
        const float4* gp = (const float4*)(gw + (size_t)e * DIM + lane * 16);
        double s = 0.0;
#pragma unroll
        for (int i = 0; i < 4; ++i) {
            float4 g = gp[i];
            s += (double)xv[i].x * g.x + (double)xv[i].y * g.y +
                 (double)xv[i].z * g.z + (double)xv[i].w * g.w;
        }
#pragma unroll
        for (int m = 32; m >= 1; m >>= 1) s += __shfl_xor(s, m, 64);
        lg[e] = s;
    }

    if (lane == 0) {
        int e0 = 0; double b0 = lg[0];
#pragma unroll
        for (int e = 1; e < NEXP; ++e)
            if (lg[e] > b0) { b0 = lg[e]; e0 = e; }
        int e1 = -1; double b1 = -1.0e300;
#pragma unroll
        for (int e = 0; e < NEXP; ++e)
            if (e != e0 && lg[e] > b1) { b1 = lg[e]; e1 = e; }

        float p0 = (float)(1.0 / (1.0 + exp(b1 - b0)));
        float p1 = 1.0f - p0;

        int pos0 = atomicAdd(&cnt[e0], 1);
        slot_list[e0 * T_TOK + pos0] = 2 * t;
        slot_w[2 * t] = p0;
        int pos1 = atomicAdd(&cnt[e1], 1);
        slot_list[e1 * T_TOK + pos1] = 2 * t + 1;
        slot_w[2 * t + 1] = p1;
    }
}

// ---------------------------------------------------------------------------
// Kernel 2: gathered GEMM, fused w1/w3 + SwiGLU. C-tile 128 slots x (64+64).
// grid (HID/64=44, ceilT/128, NEXP), early-exit on empty m-block.
// (byte-identical to r11)
// ---------------------------------------------------------------------------
__global__ __launch_bounds__(256) void ffn1_k(
    const unsigned short* __restrict__ xb, const unsigned short* __restrict__ w1b,
    const unsigned short* __restrict__ w3b, const int* __restrict__ cnt,
    const int* __restrict__ slot_list, unsigned short* __restrict__ h_ws)
{
    __shared__ unsigned short As[3][128 * 32];
    __shared__ unsigned short B1s[3][64 * 32];
    __shared__ unsigned short B2s[3][64 * 32];
    __shared__ int slots_s[128];

    const int e = blockIdx.z;
    const int cntE = cnt[e];
    const int m0 = blockIdx.y * 128;
    if (m0 >= cntE) return;
    const int n0 = blockIdx.x * 64;
    const int tid = threadIdx.x;
    const int wave = tid >> 6, lane = tid & 63;

    if (tid < 128) {
        int idx = m0 + tid;
        slots_s[tid] = (idx < cntE) ? slot_list[e * T_TOK + idx] : -1;
    }
    __syncthreads();

    const int rr = lane >> 2;
    const int qsw = (lane & 3) ^ ((rr >> 1) & 3);
    const unsigned short* gsrc[4];
    unsigned short *l0[4], *l1[4], *l2[4];
    if (wave < 2) {
#pragma unroll
        for (int i = 0; i < 4; ++i) {
            int row = wave * 64 + i * 16 + rr;
            int slot = slots_s[row];
            int tok = (slot >= 0) ? (slot >> 1) : 0;
            gsrc[i] = xb + (size_t)tok * DIM + qsw * 8;
            l0[i] = &As[0][(wave * 64 + i * 16) * 32];
            l1[i] = &As[1][(wave * 64 + i * 16) * 32];
            l2[i] = &As[2][(wave * 64 + i * 16) * 32];
        }
    } else if (wave == 2) {
#pragma unroll
        for (int i = 0; i < 4; ++i) {
            int row = i * 16 + rr;
            gsrc[i] = w1b + ((size_t)e * HID + n0 + row) * DIM + qsw * 8;
            l0[i] = &B1s[0][(i * 16) * 32];
            l1[i] = &B1s[1][(i * 16) * 32];
            l2[i] = &B1s[2][(i * 16) * 32];
        }
    } else {
#pragma unroll
        for (int i = 0; i < 4; ++i) {
            int row = i * 16 + rr;
            gsrc[i] = w3b + ((size_t)e * HID + n0 + row) * DIM + qsw * 8;
            l0[i] = &B2s[0][(i * 16) * 32];
            l1[i] = &B2s[1][(i * 16) * 32];
            l2[i] = &B2s[2][(i * 16) * 32];
        }
    }

    const int wm = wave >> 1, wn = wave & 1;
    const int lrow = lane & 15, quad = lane >> 4;
    const int ksw = (quad ^ ((lrow >> 1) & 3)) * 8;

    f32x4 acc1[4][2], acc2[4][2];
    const f32x4 zf = {0.f, 0.f, 0.f, 0.f};
#pragma unroll
    for (int mi = 0; mi < 4; ++mi)
#pragma unroll
        for (int ni = 0; ni < 2; ++ni) { acc1[mi][ni] = zf; acc2[mi][ni] = zf; }

#define FFN1_STG(N) do { \
    gl_lds16(gsrc[0], l##N[0]); gl_lds16(gsrc[1], l##N[1]); \
    gl_lds16(gsrc[2], l##N[2]); gl_lds16(gsrc[3], l##N[3]); \
    gsrc[0] += 32; gsrc[1] += 32; gsrc[2] += 32; gsrc[3] += 32; } while (0)

#define FFN1_COMP(N) do { \
    bf16x8 af[4], b1f[2], b2f[2]; \
    _Pragma("unroll") \
    for (int mi = 0; mi < 4; ++mi) \
        af[mi] = *(const bf16x8*)&As[N][(wm * 64 + mi * 16 + lrow) * 32 + ksw]; \
    _Pragma("unroll") \
    for (int ni = 0; ni < 2; ++ni) { \
        b1f[ni] = *(const bf16x8*)&B1s[N][(wn * 32 + ni * 16 + lrow) * 32 + ksw]; \
        b2f[ni] = *(const bf16x8*)&B2s[N][(wn * 32 + ni * 16 + lrow) * 32 + ksw]; \
    } \
    __builtin_amdgcn_s_setprio(1); \
    _Pragma("unroll") \
    for (int mi = 0; mi < 4; ++mi) { \
        acc1[mi][0] = __builtin_amdgcn_mfma_f32_16x16x32_bf16(af[mi], b1f[0], acc1[mi][0], 0, 0, 0); \
        acc1[mi][1] = __builtin_amdgcn_mfma_f32_16x16x32_bf16(af[mi], b1f[1], acc1[mi][1], 0, 0, 0); \
        acc2[mi][0] = __builtin_amdgcn_mfma_f32_16x16x32_bf16(af[mi], b2f[0], acc2[mi][0], 0, 0, 0); \
        acc2[mi][1] = __builtin_amdgcn_mfma_f32_16x16x32_bf16(af[mi], b2f[1], acc2[mi][1], 0, 0, 0); \
    } \
    __builtin_amdgcn_s_setprio(0); } while (0)

    FFN1_STG(0);
    FFN1_STG(1);
    WAIT4;

    for (int g = 0; g < 10; ++g) {
        FFN1_STG(2); FFN1_COMP(0); WAIT4;
        FFN1_STG(0); FFN1_COMP(1); WAIT4;
        FFN1_STG(1); FFN1_COMP(2); WAIT4;
    }
    FFN1_COMP(0); WAIT0;
    FFN1_COMP(1);

#undef FFN1_STG
#undef FFN1_COMP

#pragma unroll
    for (int mi = 0; mi < 4; ++mi) {
#pragma unroll
        for (int r = 0; r < 4; ++r) {
            int mloc = wm * 64 + mi * 16 + quad * 4 + r;
            int slot = slots_s[mloc];
            if (slot >= 0) {
                unsigned short* hrow =
                    h_ws + (size_t)slot * HID + n0 + wn * 32 + lrow;
#pragma unroll
                for (int ni = 0; ni < 2; ++ni) {
                    float a1 = acc1[mi][ni][r], a3 = acc2[mi][ni][r];
                    float hv = (a1 / (1.f + __expf(-a1))) * a3;
                    hrow[ni * 16] = (unsigned short)(f2bf_u(hv) >> 16);
                }
            }
        }
    }
}

// ---------------------------------------------------------------------------
// Kernel 3: gathered GEMM y = h @ w2^T, scale by routing weight, PLAIN STORE
// into per-slot y_ws. C-tile 128 x 128. grid (DIM/128=8, ceilT/128, NEXP).
// (byte-identical to r11)
// ---------------------------------------------------------------------------
__global__ __launch_bounds__(256) void ffn2_k(
    const unsigned short* __restrict__ h_ws, const unsigned short* __restrict__ w2b,
    const int* __restrict__ cnt, const int* __restrict__ slot_list,
    const float* __restrict__ slot_w, float* __restrict__ y_ws)
{
    __shared__ unsigned short As[3][128 * 32];
    __shared__ unsigned short Bs[3][128 * 32];
    __shared__ int slots_s[128];
    __shared__ float wgt_s[128];

    const int e = blockIdx.z;
    const int cntE = cnt[e];
    const int m0 = blockIdx.y * 128;
    if (m0 >= cntE) return;
    const int n0 = blockIdx.x * 128;
    const int tid = threadIdx.x;
    const int wave = tid >> 6, lane = tid & 63;

    if (tid < 128) {
        int idx = m0 + tid;
        int s = (idx < cntE) ? slot_list[e * T_TOK + idx] : -1;
        slots_s[tid] = s;
        wgt_s[tid] = (s >= 0) ? slot_w[s] : 0.f;
    }
    __syncthreads();

    const int rr = lane >> 2;
    const int qsw = (lane & 3) ^ ((rr >> 1) & 3);
    const unsigned short* gsrc[4];
    unsigned short *l0[4], *l1[4], *l2[4];
    if (wave < 2) {
#pragma unroll
        for (int i = 0; i < 4; ++i) {
            int row = wave * 64 + i * 16 + rr;
            int slot = slots_s[row];
            int s = (slot >= 0) ? slot : 0;
            gsrc[i] = h_ws + (size_t)s * HID + qsw * 8;
            l0[i] = &As[0][(wave * 64 + i * 16) * 32];
            l1[i] = &As[1][(wave * 64 + i * 16) * 32];
            l2[i] = &As[2][(wave * 64 + i * 16) * 32];
        }
    } else {
#pragma unroll
        for (int i = 0; i < 4; ++i) {
            int row = (wave - 2) * 64 + i * 16 + rr;
            gsrc[i] = w2b + ((size_t)e * DIM + n0 + row) * HID + qsw * 8;
            l0[i] = &Bs[0][((wave - 2) * 64 + i * 16) * 32];
            l1[i] = &Bs[1][((wave - 2) * 64 + i * 16) * 32];
            l2[i] = &Bs[2][((wave - 2) * 64 + i * 16) * 32];
        }
    }

    const int wm = wave >> 1, wn = wave & 1;
    const int lrow = lane & 15, quad = lane >> 4;
    const int ksw = (quad ^ ((lrow >> 1) & 3)) * 8;

    f32x4 acc[4][4];
    const f32x4 zf = {0.f, 0.f, 0.f, 0.f};
#pragma unroll
    for (int mi = 0; mi < 4; ++mi)
#pragma unroll
        for (int ni = 0; ni < 4; ++ni) acc[mi][ni] = zf;

#define FFN2_STG(N) do { \
    gl_lds16(gsrc[0], l##N[0]); gl_lds16(gsrc[1], l##N[1]); \
    gl_lds16(gsrc[2], l##N[2]); gl_lds16(gsrc[3], l##N[3]); \
    gsrc[0] += 32; gsrc[1] += 32; gsrc[2] += 32; gsrc[3] += 32; } while (0)

#define FFN2_COMP(N) do { \
    bf16x8 af[4], bf[4]; \
    _Pragma("unroll") \
    for (int mi = 0; mi < 4; ++mi) \
        af[mi] = *(const bf16x8*)&As[N][(wm * 64 + mi * 16 + lrow) * 32 + ksw]; \
    _Pragma("unroll") \
    for (int ni = 0; ni < 4; ++ni) \
        bf[ni] = *(const bf16x8*)&Bs[N][(wn * 64 + ni * 16 + lrow) * 32 + ksw]; \
    __builtin_amdgcn_s_setprio(1); \
    _Pragma("unroll") \
    for (int mi = 0; mi < 4; ++mi) { \
        acc[mi][0] = __builtin_amdgcn_mfma_f32_16x16x32_bf16(af[mi], bf[0], acc[mi][0], 0, 0, 0); \
        acc[mi][1] = __builtin_amdgcn_mfma_f32_16x16x32_bf16(af[mi], bf[1], acc[mi][1], 0, 0, 0); \
        acc[mi][2] = __builtin_amdgcn_mfma_f32_16x16x32_bf16(af[mi], bf[2], acc[mi][2], 0, 0, 0); \
        acc[mi][3] = __builtin_amdgcn_mfma_f32_16x16x32_bf16(af[mi], bf[3], acc[mi][3], 0, 0, 0); \
    } \
    __builtin_amdgcn_s_setprio(0); } while (0)

    // NST = 88.
    FFN2_STG(0);
    FFN2_STG(1);
    WAIT4;

    for (int g = 0; g < 28; ++g) {
        FFN2_STG(2); FFN2_COMP(0); WAIT4;
        FFN2_STG(0); FFN2_COMP(1); WAIT4;
        FFN2_STG(1); FFN2_COMP(2); WAIT4;
    }
    FFN2_STG(2); FFN2_COMP(0); WAIT4;
    FFN2_STG(0); FFN2_COMP(1); WAIT4;
    FFN2_COMP(2); WAIT0;
    FFN2_COMP(0);

#undef FFN2_STG
#undef FFN2_COMP

#pragma unroll
    for (int mi = 0; mi < 4; ++mi) {
#pragma unroll
        for (int r = 0; r < 4; ++r) {
            int mloc = wm * 64 + mi * 16 + quad * 4 + r;
            int slot = slots_s[mloc];
            if (slot >= 0) {
                float w = wgt_s[mloc];
                float* yrow = y_ws + (size_t)slot * DIM + n0 + wn * 64 + lrow;
#pragma unroll
                for (int ni = 0; ni < 4; ++ni)
                    yrow[ni * 16] = acc[mi][ni][r] * w;
            }
        }
    }
}

// ---------------------------------------------------------------------------
// Kernel 4: combine. out[t] = y[2t] + y[2t+1]  (both already weight-scaled).
// ---------------------------------------------------------------------------
__global__ __launch_bounds__(256) void combine_k(
    const float* __restrict__ y, float* __restrict__ out)
{
    int i = blockIdx.x * 256 + threadIdx.x;      // i in [0, 8192*256)
    int t = i >> 8, d = i & 255;
    const float4* a = (const float4*)(y + (size_t)(2 * t) * DIM) + d;
    const float4* b = (const float4*)(y + (size_t)(2 * t + 1) * DIM) + d;
    float4 va = *a, vb = *b;
    float4 o = {va.x + vb.x, va.y + vb.y, va.z + vb.z, va.w + vb.w};
    ((float4*)(out + (size_t)t * DIM))[d] = o;
}

// ---------------------------------------------------------------------------
// Workspace layout (bytes):
//   [0, 256)                 cnt[8]                (zeroed by prep_k)
//   [256, +262144)           slot_list[8][8192]
//   [+262144, +65536)        slot_w[16384]
//   [327936, +92274688)      h_ws   bf16 [16384][2816]
//   [92602624, +16777216)    x_bf   bf16 [8192][1024]  (written by router_k)
//   [109379840, +46137344)   w1_bf  bf16 [8][2816][1024]
//   [155517184, +46137344)   w3_bf
//   [201654528, +46137344)   w2_bf  bf16 [8][1024][2816]
//   y_ws f32 [16384][1024] = 67108864 B ALIASES [92602624, 159711488):
//   x_bf + w1_bf + first 4.2MB of w3_bf — all dead after ffn1 completes;
//   stream order (ffn1 -> ffn2 -> combine -> next-iter prep/router rewrites)
//   makes this safe.
// ---------------------------------------------------------------------------
extern "C" void kernel_launch(void* const* d_in, const int* in_sizes, int n_in,
                              void* d_out, int out_size, void* d_ws, size_t ws_size,
                              hipStream_t stream) {
    const float* x  = (const float*)d_in[0];
    const float* gw = (const float*)d_in[1];
    const float* w1 = (const float*)d_in[2];
    const float* w2 = (const float*)d_in[3];
    const float* w3 = (const float*)d_in[4];
    float* out = (float*)d_out;

    char* ws = (char*)d_ws;
    int*   cnt       = (int*)ws;
    int*   slot_list = (int*)(ws + 256);
    float* slot_w    = (float*)(ws + 256 + NEXP * T_TOK * 4);
    unsigned short* h_ws = (unsigned short*)(ws + 327936);
    unsigned short* x_bf = (unsigned short*)(ws + 92602624);
    unsigned short* w1_bf = (unsigned short*)(ws + 109379840);
    unsigned short* w3_bf = (unsigned short*)(ws + 155517184);
    unsigned short* w2_bf = (unsigned short*)(ws + 201654528);
    float* y_ws = (float*)(ws + 92602624);   // aliases x_bf/w1_bf (dead post-ffn1)

    const int nw = NEXP * HID * DIM / 8;         // 2883584
    prep_k<<<(3 * nw + 255) / 256, 256, 0, stream>>>(
        w1, w3, w2, w1_bf, w3_bf, w2_bf, cnt);
    router_k<<<T_TOK / 4, 256, 0, stream>>>(
        x, gw, x_bf, cnt, slot_list, slot_w);
    ffn1_k<<<dim3(HID / 64, T_TOK / 128, NEXP), 256, 0, stream>>>(
        x_bf, w1_bf, w3_bf, cnt, slot_list, h_ws);
    ffn2_k<<<dim3(DIM / 128, T_TOK / 128, NEXP), 256, 0, stream>>>(
        h_ws, w2_bf, cnt, slot_list, slot_w, y_ws);
    combine_k<<<T_TOK, 256, 0, stream>>>(y_ws, out);
}